// Round 6
// baseline (321.525 us; speedup 1.0000x reference)
//
#include <hip/hip_runtime.h>
#include <math.h>

using bf16x8 = __attribute__((ext_vector_type(8))) short;
using f32x4  = __attribute__((ext_vector_type(4))) float;
using u16x8  = __attribute__((ext_vector_type(8))) unsigned short;
using u16x4  = __attribute__((ext_vector_type(4))) unsigned short;

constexpr int Bb = 4, Tt = 2048, Ee = 1024, Hh = 16;
constexpr int Mm = Bb * Tt;   // 8192
constexpr int E3 = 3 * Ee;    // 3072

__device__ __forceinline__ unsigned short f2bf(float f) {
  union { float f; unsigned int u; } c; c.f = f;
  unsigned int u = c.u;
  u += 0x7fffu + ((u >> 16) & 1u);   // RNE
  return (unsigned short)(u >> 16);
}

__device__ __forceinline__ f32x4 mfma16(bf16x8 a, bf16x8 b, f32x4 c) {
  return __builtin_amdgcn_mfma_f32_16x16x32_bf16(a, b, c, 0, 0, 0);
}

__device__ __forceinline__ void gload_lds16(const unsigned short* g, unsigned short* l) {
  __builtin_amdgcn_global_load_lds(
      (const __attribute__((address_space(1))) unsigned int*)g,
      (__attribute__((address_space(3))) unsigned int*)l, 16, 0, 0);
}

#define BAR()   __builtin_amdgcn_s_barrier()
#define LGKM0() do { asm volatile("s_waitcnt lgkmcnt(0)" ::: "memory"); \
                     __builtin_amdgcn_sched_barrier(0); } while (0)
#define VMC(n)  asm volatile("s_waitcnt vmcnt(" #n ")" ::: "memory")

// ---------------------------------------------------------------------------
// fused fp32 -> bf16 conversion for all three inputs (one launch)
// ---------------------------------------------------------------------------
__global__ void cvt_all(const float* __restrict__ q, const float* __restrict__ iw,
                        const float* __restrict__ ow, unsigned short* __restrict__ qb,
                        unsigned short* __restrict__ wib, unsigned short* __restrict__ wob) {
  constexpr int nQ = Mm * Ee / 8, nI = E3 * Ee / 8, nO = Ee * Ee / 8;
  int i = blockIdx.x * 256 + threadIdx.x;
  const float* in; unsigned short* out;
  if (i < nQ) { in = q; out = qb; }
  else if (i < nQ + nI) { in = iw; out = wib; i -= nQ; }
  else if (i < nQ + nI + nO) { in = ow; out = wob; i -= nQ + nI; }
  else return;
  const float4* p = (const float4*)in + (size_t)i * 2;
  const float4 a = p[0], b = p[1];
  u16x8 r = { f2bf(a.x), f2bf(a.y), f2bf(a.z), f2bf(a.w),
              f2bf(b.x), f2bf(b.y), f2bf(b.z), f2bf(b.w) };
  *(u16x8*)(out + (size_t)i * 8) = r;
}

// ---------------------------------------------------------------------------
// 8-phase 256x256 GEMM, round-6 re-stagger: every stage lands 5-7 phases
// after issue (r5 bug: Ae(u+1)/Bo(u+1) staged 1-2 phases before their guard
// -> counted vmcnt degenerated to a drain).
// Tile u phases (slots: Xe(u)->(2u)&3, Xo(u)->(2u+1)&3, A and B rings
// independent; stage targets are always slots freed by THIS tile's earlier
// phase reads, post-barrier):
//   P1: read Ae(u),Be(u); MFMA Q(0,0);            vmcnt(8)  [Bo(u),Ao(u) landed]
//   P2: read Bo(u); stage Ae(u+2),Be(u+2); Q(0,1)
//   P3: read Ao(u); stage Bo(u+2);         Q(1,1)
//   P4: (regs only); stage Ao(u+2);        Q(1,0); vmcnt(12) [Ae/Be(u+1) landed]
// Guard counts from the per-tile issue stream [P2:4][P3:2][P4:2]:
//   Ao(u) @P4(u-2): 4+2+2 issued after -> vmcnt(8), 5-phase distance.
//   Ae/Be(u+1) @P2(u-1): 2+2+4+2+2 = 12 after -> vmcnt(12), 7-phase distance.
// Tail stages clamp kt (redundant loads into freed slots - keeps counts
// uniform, provably never read). st_16x32 swizzle both-sides (rule #21).
// ---------------------------------------------------------------------------
template <int MH, int NH>
__device__ __forceinline__ void mmaQuad(f32x4 (&acc)[8][4], const bf16x8* af, const bf16x8* bf) {
  __builtin_amdgcn_s_setprio(1);
#pragma unroll
  for (int i = 0; i < 4; ++i)
#pragma unroll
    for (int j = 0; j < 2; ++j) {
      acc[MH * 4 + i][NH * 2 + j] = mfma16(af[i * 2 + 0], bf[j * 2 + 0], acc[MH * 4 + i][NH * 2 + j]);
      acc[MH * 4 + i][NH * 2 + j] = mfma16(af[i * 2 + 1], bf[j * 2 + 1], acc[MH * 4 + i][NH * 2 + j]);
    }
  __builtin_amdgcn_s_setprio(0);
}

__global__ __launch_bounds__(512, 2)
void gemm_bt8(const unsigned short* __restrict__ A, const unsigned short* __restrict__ Bw,
              const float* __restrict__ bias, unsigned short* __restrict__ Cout,
              int N, int K) {
  __shared__ alignas(16) unsigned short lds8[8 * 8192];  // A slots 0-3, B slots 4-7
  const int tid = threadIdx.x;
  const int wave = tid >> 6, lane = tid & 63;
  const int l15 = lane & 15, quad = lane >> 4;
  const int wm = wave >> 2, wn = wave & 3;
  const int nt = K >> 6;

  // XCD-aware bijective block swizzle (gridDim.x % 8 == 0); ntile-fast within
  // a chunk: 48-block chunk = 4 M-panels x 12 N-tiles -> 2MB A + 6MB B / XCD.
  const int cpx = gridDim.x >> 3;
  const int swz = (blockIdx.x & 7) * cpx + (blockIdx.x >> 3);
  const int ntn = N >> 8;
  const int ntile = swz % ntn, mtile = swz / ntn;
  const int row0 = mtile << 8, col0 = ntile << 8;

  // ---- per-lane staging constants (inverse-swizzled global source) ----
  int lrow[2], lcbh[2];                               // row, col(ushort) within half
#pragma unroll
  for (int j = 0; j < 2; ++j) {
    const int linoff = (j * 512 + tid) << 4;          // linear byte off in 16KB half
    const int logical = linoff ^ (((linoff >> 9) & 1) << 5);
    lrow[j] = logical >> 7;
    lcbh[j] = (logical & 127) >> 1;
  }
  unsigned int aoff[2][2], boff[2][2];                // [half][j] ushort offsets
#pragma unroll
  for (int j = 0; j < 2; ++j) {
    aoff[0][j] = (unsigned int)(row0 + lrow[j]) * K + lcbh[j];
    aoff[1][j] = (unsigned int)(row0 + 128 + lrow[j]) * K + lcbh[j];
    boff[0][j] = (unsigned int)(col0 + lrow[j]) * K + lcbh[j];
    boff[1][j] = (unsigned int)(col0 + 128 + lrow[j]) * K + lcbh[j];
  }
  const int ldsW = wave * 512;                        // ushort idx of this wave's chunk

  // ---- per-lane ds_read offsets (swizzled), same for both halves ----
  int aro[8], bro[4];
#pragma unroll
  for (int i = 0; i < 4; ++i)
#pragma unroll
    for (int kq = 0; kq < 2; ++kq) {
      int lb = (i * 32 + wm * 16 + l15) * 128 + kq * 64 + quad * 16;
      lb ^= ((lb >> 9) & 1) << 5;
      aro[i * 2 + kq] = lb;
    }
#pragma unroll
  for (int i = 0; i < 2; ++i)
#pragma unroll
    for (int kq = 0; kq < 2; ++kq) {
      int lb = (i * 64 + wn * 16 + l15) * 128 + kq * 64 + quad * 16;
      lb ^= ((lb >> 9) & 1) << 5;
      bro[i * 2 + kq] = lb;
    }

  f32x4 acc[8][4];
#pragma unroll
  for (int i = 0; i < 8; ++i)
#pragma unroll
    for (int j = 0; j < 4; ++j) acc[i][j] = f32x4{0.f, 0.f, 0.f, 0.f};
  bf16x8 af[8], bf0[4], bf1[4];

  auto stageA = [&](int slot, int half, int kt) __attribute__((always_inline)) {
#pragma unroll
    for (int j = 0; j < 2; ++j)
      gload_lds16(A + (size_t)aoff[half][j] + kt * 64,
                  &lds8[slot * 8192 + j * 4096 + ldsW]);
  };
  auto stageB = [&](int slot, int half, int kt) __attribute__((always_inline)) {
#pragma unroll
    for (int j = 0; j < 2; ++j)
      gload_lds16(Bw + (size_t)boff[half][j] + kt * 64,
                  &lds8[(4 + slot) * 8192 + j * 4096 + ldsW]);
  };
  auto ldA = [&](int slot) __attribute__((always_inline)) {
    const char* base = (const char*)lds8 + slot * 16384;
#pragma unroll
    for (int x = 0; x < 8; ++x) af[x] = *(const bf16x8*)(base + aro[x]);
  };
  auto ldB = [&](bf16x8* bf, int slot) __attribute__((always_inline)) {
    const char* base = (const char*)lds8 + (4 + slot) * 16384;
#pragma unroll
    for (int x = 0; x < 4; ++x) bf[x] = *(const bf16x8*)(base + bro[x]);
  };

  // ---- prologue: tiles 0 and 1 fully staged, full drain ----
  stageA(0, 0, 0); stageA(1, 1, 0);
  stageB(0, 0, 0); stageB(1, 1, 0);
  stageA(2, 0, 1); stageA(3, 1, 1);
  stageB(2, 0, 1); stageB(3, 1, 1);
  VMC(0); BAR();

  for (int u = 0; u < nt; ++u) {
    const int sae = (2 * u) & 3, sao = (2 * u + 1) & 3;
    const int t2 = (u + 2 < nt) ? u + 2 : nt - 1;
    // P1: read Ae(u),Be(u); MFMA (0,0)
    ldA(sae); ldB(bf0, sae);
    BAR(); LGKM0();
    mmaQuad<0, 0>(acc, af, bf0);
    VMC(8); BAR();                     // Bo(u),Ao(u) landed (issued u-2)
    // P2: read Bo(u); stage Ae(u+2),Be(u+2) (slots freed by P1 reads)
    ldB(bf1, sao);
    stageA(sae, 0, t2); stageB(sae, 0, t2);
    BAR(); LGKM0();
    mmaQuad<0, 1>(acc, af, bf1);
    BAR();
    // P3: read Ao(u); stage Bo(u+2) (slot freed by P2 read)
    ldA(sao);
    stageB(sao, 1, t2);
    BAR(); LGKM0();
    mmaQuad<1, 1>(acc, af, bf1);
    BAR();
    // P4: regs only; stage Ao(u+2) (slot freed by P3 read)
    stageA(sao, 1, t2);
    mmaQuad<1, 0>(acc, af, bf0);
    VMC(12); BAR();                    // Ae(u+1),Be(u+1) landed (issued u-1 P2)
  }

  // ---- epilogue: bias + QSCALE + bf16 store ----
#pragma unroll
  for (int mi = 0; mi < 8; ++mi)
#pragma unroll
    for (int ni = 0; ni < 4; ++ni) {
      const int col = col0 + ni * 64 + wn * 16 + l15;
      const float bv = bias[col];
      const float scale = (col < 1024) ? 0.18033688f : 1.0f;  // log2(e)/8 on q-part
#pragma unroll
      for (int r = 0; r < 4; ++r) {
        const int row = row0 + mi * 32 + wm * 16 + quad * 4 + r;
        Cout[(size_t)row * N + col] = f2bf((acc[mi][ni][r] + bv) * scale);
      }
    }
}

// ---------------------------------------------------------------------------
// C[M,N] = A[M,K] * Bw[N,K]^T + bias  (bf16 MFMA, m97-style) — gemm2 only
// ---------------------------------------------------------------------------
template <bool OUT_BF16, bool QSCALE>
__global__ __launch_bounds__(256, 2)
void gemm_bt(const unsigned short* __restrict__ A, const unsigned short* __restrict__ Bw,
             const float* __restrict__ bias, void* __restrict__ Cout, int N, int K) {
  __shared__ alignas(16) unsigned short As[128 * 32];
  __shared__ alignas(16) unsigned short Bs[128 * 32];
  const int tid = threadIdx.x;
  const int wave = tid >> 6, lane = tid & 63;
  const int l15 = lane & 15, quad = lane >> 4;
  const int wr = wave >> 1, wc = wave & 1;
  const int row0 = blockIdx.y * 128, col0 = blockIdx.x * 128;
  const int srow = lane >> 2, sslot = lane & 3;

  f32x4 acc[4][4];
#pragma unroll
  for (int i = 0; i < 4; ++i)
#pragma unroll
    for (int j = 0; j < 4; ++j) acc[i][j] = f32x4{0.f, 0.f, 0.f, 0.f};

  for (int k0 = 0; k0 < K; k0 += 32) {
#pragma unroll
    for (int t = 0; t < 2; ++t) {
      const int rA = wave * 32 + t * 16 + srow;          // 0..127
      const int g = sslot ^ ((rA >> 1) & 3);             // swizzled global chunk
      gload_lds16(A  + (size_t)(row0 + rA) * K + k0 + g * 8, &As[(wave * 32 + t * 16) * 32]);
      gload_lds16(Bw + (size_t)(col0 + rA) * K + k0 + g * 8, &Bs[(wave * 32 + t * 16) * 32]);
    }
    __syncthreads();

    bf16x8 af[4], bfr[4];
#pragma unroll
    for (int mi = 0; mi < 4; ++mi) {
      const int m = wr * 64 + mi * 16 + l15;
      af[mi] = *(const bf16x8*)&As[m * 32 + (quad ^ ((m >> 1) & 3)) * 8];
    }
#pragma unroll
    for (int ni = 0; ni < 4; ++ni) {
      const int n = wc * 64 + ni * 16 + l15;
      bfr[ni] = *(const bf16x8*)&Bs[n * 32 + (quad ^ ((n >> 1) & 3)) * 8];
    }
#pragma unroll
    for (int mi = 0; mi < 4; ++mi)
#pragma unroll
      for (int ni = 0; ni < 4; ++ni) acc[mi][ni] = mfma16(af[mi], bfr[ni], acc[mi][ni]);
    __syncthreads();
  }

#pragma unroll
  for (int mi = 0; mi < 4; ++mi)
#pragma unroll
    for (int ni = 0; ni < 4; ++ni) {
      const int col = col0 + wc * 64 + ni * 16 + l15;
      const float bv = bias[col];
      const float scale = (QSCALE && col < 1024) ? 0.18033688f : 1.0f;  // log2(e)/8
#pragma unroll
      for (int r = 0; r < 4; ++r) {
        const int row = row0 + wr * 64 + mi * 16 + quad * 4 + r;
        float v = (acc[mi][ni][r] + bv) * scale;
        if (OUT_BF16)
          ((unsigned short*)Cout)[(size_t)row * N + col] = f2bf(v);
        else
          ((float*)Cout)[(size_t)row * N + col] = v;
      }
    }
}

// ---------------------------------------------------------------------------
// V transpose: vt[b][h][d][t] <- qkv v-part [b][t][2048 + h*64 + d]
// ---------------------------------------------------------------------------
__global__ __launch_bounds__(256, 2)
void transpose_v(const unsigned short* __restrict__ qkv, unsigned short* __restrict__ vt) {
  __shared__ unsigned short L[128][66];
  const int tid = threadIdx.x;
  const int bh = blockIdx.x, b = bh >> 4, h = bh & 15;
  const int t0 = blockIdx.y * 128;
#pragma unroll
  for (int p = 0; p < 8; ++p) {
    const int tl = p * 16 + (tid >> 4);
    const int d = (tid & 15) * 4;
    *(u16x4*)&L[tl][d] = *(const u16x4*)(qkv + (size_t)(b * Tt + t0 + tl) * E3 + 2 * Ee + h * 64 + d);
  }
  __syncthreads();
#pragma unroll
  for (int p = 0; p < 8; ++p) {
    const int dw = (tid >> 5) * 8 + p;
    const int tw = (tid & 31) * 4;
    u16x4 w = { L[tw][dw], L[tw + 1][dw], L[tw + 2][dw], L[tw + 3][dw] };
    *(u16x4*)(vt + ((size_t)bh * 64 + dw) * Tt + t0 + tw) = w;
  }
}

// ---------------------------------------------------------------------------
// Fused attention, sub-tile software pipeline (proven 134 µs version).
// Wave = 64 q-rows x 2048 keys, barrier-free, per-wave-private LDS P slab
// (64x64 bf16, XOR-swizzled). 3 failed restructures (r1-r3) confirmed:
// deep prefetch + 4-chain ILP at 2 waves/SIMD beats any register-dieted
// higher-occupancy variant. Do not shrink per-wave state.
// ---------------------------------------------------------------------------
__global__ __launch_bounds__(256, 2)
void attn_mfma6(const unsigned short* __restrict__ qkv,
                const unsigned short* __restrict__ vt,
                unsigned short* __restrict__ ctx) {
  __shared__ alignas(16) unsigned short Ps[4 * 4096];  // per-wave 64x64 bf16
  const int tid = threadIdx.x;
  const int wave = tid >> 6, lane = tid & 63;
  const int l15 = lane & 15, quad = lane >> 4;
  const int bh = blockIdx.x, b = bh >> 4, h = bh & 15;
  const int q0 = blockIdx.y * 256 + wave * 64;
  unsigned short* const ps = &Ps[wave * 4096];
  const int swz = l15 & 14;

  bf16x8 qa[4][2];
#pragma unroll
  for (int qi = 0; qi < 4; ++qi)
#pragma unroll
    for (int kf = 0; kf < 2; ++kf)
      qa[qi][kf] = *(const bf16x8*)(qkv +
          (size_t)(b * Tt + q0 + qi * 16 + l15) * E3 + h * 64 + kf * 32 + quad * 8);

  f32x4 o[4][4], ol[4];
#pragma unroll
  for (int qi = 0; qi < 4; ++qi) {
    ol[qi] = f32x4{0.f, 0.f, 0.f, 0.f};
#pragma unroll
    for (int di = 0; di < 4; ++di) o[qi][di] = f32x4{0.f, 0.f, 0.f, 0.f};
  }
  bf16x8 ones;
#pragma unroll
  for (int i = 0; i < 8; ++i) ones[i] = (short)0x3F80;  // bf16 1.0

  const unsigned short* kp = qkv + (size_t)(b * Tt + l15) * E3 + Ee + h * 64 + quad * 8;
  const unsigned short* vp = vt + ((size_t)bh * 64 + l15) * Tt + quad * 8;

  bf16x8 kb[4][2], vb[4][2];
#pragma unroll
  for (int ki = 0; ki < 4; ++ki)
#pragma unroll
    for (int kf = 0; kf < 2; ++kf)
      kb[ki][kf] = *(const bf16x8*)(kp + (size_t)ki * 16 * E3 + kf * 32);
#pragma unroll
  for (int di = 0; di < 4; ++di)
#pragma unroll
    for (int kf = 0; kf < 2; ++kf)
      vb[di][kf] = *(const bf16x8*)(vp + di * 16 * Tt + kf * 32);
  kp += 64 * E3;   // -> tile 1 (reload source)
  vp += 64;        // -> tile 1 (next vb reload)

  f32x4 sp[4], sn[4];

  auto expwrite = [&](int slot) __attribute__((always_inline)) {
#pragma unroll
    for (int qi = 0; qi < 4; ++qi) {
      const float e0 = __builtin_amdgcn_exp2f(sp[qi][0]);
      const float e1 = __builtin_amdgcn_exp2f(sp[qi][1]);
      const float e2 = __builtin_amdgcn_exp2f(sp[qi][2]);
      const float e3 = __builtin_amdgcn_exp2f(sp[qi][3]);
      uint2 w;  // truncate-to-bf16 pairs (bias cancels: denom uses same P)
      w.x = __builtin_amdgcn_perm(__float_as_uint(e1), __float_as_uint(e0), 0x07060302u);
      w.y = __builtin_amdgcn_perm(__float_as_uint(e3), __float_as_uint(e2), 0x07060302u);
      *(uint2*)(ps + (qi * 16 + l15) * 64 + (((slot * 4 + quad) ^ swz) << 2)) = w;
    }
  };
  auto Sstep = [&](int ki) __attribute__((always_inline)) {
#pragma unroll
    for (int qi = 0; qi < 4; ++qi) {
      sn[qi] = mfma16(kb[ki][0], qa[qi][0], f32x4{0.f, 0.f, 0.f, 0.f});
      sn[qi] = mfma16(kb[ki][1], qa[qi][1], sn[qi]);
    }
  };
  auto copy_sp = [&]() __attribute__((always_inline)) {
#pragma unroll
    for (int qi = 0; qi < 4; ++qi) sp[qi] = sn[qi];
  };
  auto pvstep = [&](bool reload_vb) __attribute__((always_inline)) {
    __builtin_amdgcn_s_setprio(1);
#pragma unroll
    for (int qi = 0; qi < 4; ++qi) {
      bf16x8 pa0 = *(const bf16x8*)(ps + (qi * 16 + l15) * 64 + (((quad * 2) ^ swz) << 2));
      bf16x8 pa1 = *(const bf16x8*)(ps + (qi * 16 + l15) * 64 + (((8 + quad * 2) ^ swz) << 2));
      ol[qi] = mfma16(pa0, ones, ol[qi]);
      ol[qi] = mfma16(pa1, ones, ol[qi]);
#pragma unroll
      for (int di = 0; di < 4; ++di) {
        o[qi][di] = mfma16(pa0, vb[di][0], o[qi][di]);
        o[qi][di] = mfma16(pa1, vb[di][1], o[qi][di]);
      }
    }
    __builtin_amdgcn_s_setprio(0);
    if (reload_vb) {
#pragma unroll
      for (int di = 0; di < 4; ++di)
#pragma unroll
        for (int kf = 0; kf < 2; ++kf)
          vb[di][kf] = *(const bf16x8*)(vp + di * 16 * Tt + kf * 32);
      vp += 64;
    }
  };

  Sstep(0); copy_sp();
  kb[0][0] = *(const bf16x8*)(kp);
  kb[0][1] = *(const bf16x8*)(kp + 32);

  for (int j = 0; j < 31; ++j) {
    expwrite(0);
    Sstep(1);
    kb[1][0] = *(const bf16x8*)(kp + (size_t)16 * E3);
    kb[1][1] = *(const bf16x8*)(kp + (size_t)16 * E3 + 32);
    copy_sp();
    expwrite(1);
    Sstep(2);
    kb[2][0] = *(const bf16x8*)(kp + (size_t)32 * E3);
    kb[2][1] = *(const bf16x8*)(kp + (size_t)32 * E3 + 32);
    copy_sp();
    expwrite(2);
    Sstep(3);
    kb[3][0] = *(const bf16x8*)(kp + (size_t)48 * E3);
    kb[3][1] = *(const bf16x8*)(kp + (size_t)48 * E3 + 32);
    kp += 64 * E3;
    copy_sp();
    expwrite(3);
    Sstep(0);
    if (j < 30) {
      kb[0][0] = *(const bf16x8*)(kp);
      kb[0][1] = *(const bf16x8*)(kp + 32);
    }
    copy_sp();
    pvstep(true);
  }
  expwrite(0); Sstep(1); copy_sp();
  expwrite(1); Sstep(2); copy_sp();
  expwrite(2); Sstep(3); copy_sp();
  expwrite(3);
  pvstep(false);

#pragma unroll
  for (int qi = 0; qi < 4; ++qi) {
    f32x4 inv;
#pragma unroll
    for (int r = 0; r < 4; ++r) inv[r] = 1.0f / ol[qi][r];
#pragma unroll
    for (int di = 0; di < 4; ++di)
#pragma unroll
      for (int r = 0; r < 4; ++r)
        ctx[(size_t)(b * Tt + q0 + qi * 16 + quad * 4 + r) * Ee + h * 64 + di * 16 + l15] =
            f2bf(o[qi][di][r] * inv[r]);
  }
}

// ---------------------------------------------------------------------------
extern "C" void kernel_launch(void* const* d_in, const int* in_sizes, int n_in,
                              void* d_out, int out_size, void* d_ws, size_t ws_size,
                              hipStream_t stream) {
  const float* query = (const float*)d_in[0];
  const float* in_w  = (const float*)d_in[1];
  const float* in_b  = (const float*)d_in[2];
  const float* out_w = (const float*)d_in[3];
  const float* out_b = (const float*)d_in[4];
  float* out = (float*)d_out;

  char* w = (char*)d_ws;
  unsigned short* qkvb = (unsigned short*)(w);                 // 48 MiB
  unsigned short* ctxb = (unsigned short*)(w + 50331648);      // 16 MiB
  unsigned short* qb   = (unsigned short*)(w + 67108864);      // 16 MiB
  unsigned short* wib  = (unsigned short*)(w + 83886080);      // 6 MiB
  unsigned short* wob  = (unsigned short*)(w + 90177536);      // 2 MiB
  unsigned short* vtb  = (unsigned short*)(w + 92274688);      // 16 MiB

  // 0) all fp32->bf16 conversions in one launch
  cvt_all<<<6144, 256, 0, stream>>>(query, in_w, out_w, qb, wib, wob);
  // 1) qkv = query @ in_w^T + in_b (q part pre-scaled by log2e/8), 8-phase 256^2
  gemm_bt8<<<dim3((E3 / 256) * (Mm / 256)), 512, 0, stream>>>(qb, wib, in_b, qkvb, E3, Ee);
  // 1b) pre-transpose V: vt[b][h][d][t]
  transpose_v<<<dim3(Bb * Hh, Tt / 128), 256, 0, stream>>>(qkvb, vtb);
  // 2) fused attention (64 q-rows/wave, proven pipeline) -> ctx
  attn_mfma6<<<dim3(Bb * Hh, Tt / 256), 256, 0, stream>>>(qkvb, vtb, ctxb);
  // 3) out = ctx @ out_w^T + out_b  (fp32 out, proven m97 kernel)
  gemm_bt<false, false><<<dim3(Ee / 128, Mm / 128), 256, 0, stream>>>(ctxb, wob, out_b, out, Ee, Ee);
}

// Round 7
// 301.986 us; speedup vs baseline: 1.0647x; 1.0647x over previous
//
#include <hip/hip_runtime.h>
#include <math.h>

using bf16x8 = __attribute__((ext_vector_type(8))) short;
using f32x4  = __attribute__((ext_vector_type(4))) float;
using u16x8  = __attribute__((ext_vector_type(8))) unsigned short;
using u16x4  = __attribute__((ext_vector_type(4))) unsigned short;

constexpr int Bb = 4, Tt = 2048, Ee = 1024, Hh = 16;
constexpr int Mm = Bb * Tt;   // 8192
constexpr int E3 = 3 * Ee;    // 3072

__device__ __forceinline__ unsigned short f2bf(float f) {
  union { float f; unsigned int u; } c; c.f = f;
  unsigned int u = c.u;
  u += 0x7fffu + ((u >> 16) & 1u);   // RNE
  return (unsigned short)(u >> 16);
}

__device__ __forceinline__ f32x4 mfma16(bf16x8 a, bf16x8 b, f32x4 c) {
  return __builtin_amdgcn_mfma_f32_16x16x32_bf16(a, b, c, 0, 0, 0);
}

__device__ __forceinline__ void gload_lds16(const unsigned short* g, unsigned short* l) {
  __builtin_amdgcn_global_load_lds(
      (const __attribute__((address_space(1))) unsigned int*)g,
      (__attribute__((address_space(3))) unsigned int*)l, 16, 0, 0);
}

// ---------------------------------------------------------------------------
// fused fp32 -> bf16 conversion for all three inputs (one launch)
// ---------------------------------------------------------------------------
__global__ void cvt_all(const float* __restrict__ q, const float* __restrict__ iw,
                        const float* __restrict__ ow, unsigned short* __restrict__ qb,
                        unsigned short* __restrict__ wib, unsigned short* __restrict__ wob) {
  constexpr int nQ = Mm * Ee / 8, nI = E3 * Ee / 8, nO = Ee * Ee / 8;
  int i = blockIdx.x * 256 + threadIdx.x;
  const float* in; unsigned short* out;
  if (i < nQ) { in = q; out = qb; }
  else if (i < nQ + nI) { in = iw; out = wib; i -= nQ; }
  else if (i < nQ + nI + nO) { in = ow; out = wob; i -= nQ + nI; }
  else return;
  const float4* p = (const float4*)in + (size_t)i * 2;
  const float4 a = p[0], b = p[1];
  u16x8 r = { f2bf(a.x), f2bf(a.y), f2bf(a.z), f2bf(a.w),
              f2bf(b.x), f2bf(b.y), f2bf(b.z), f2bf(b.w) };
  *(u16x8*)(out + (size_t)i * 8) = r;
}

// ---------------------------------------------------------------------------
// C[M,N] = A[M,K] * Bw[N,K]^T + bias  (bf16 MFMA, m97-style, BK=64).
//
// Round-7 change: BK 32->64. Cross-round accounting showed gemm1 ~ 130 us
// (~400 TF) -- the m97 structure's per-K-step fixed cost (vmcnt0+barrier
// drain ~300-600 cyc) vs only ~620 cyc MFMA/CU-step at BK=32 is ~50%
// overhead at K=1024 (32 steps). BK=64 doubles MFMA per barrier (1242 cyc)
// -> overhead ~29%. af/bfr loaded per 32-k half (register reuse; VGPR stays
// ~m97 level, no spill).
//
// LDS layout at BK=64: [128 rows][64 ushort] = 128B rows, 8 chunks of 16B.
// Conflict-free mapping: physical chunk p of row r holds logical chunk
// p ^ (r&7). Read af at logical chunk (kq*4+quad) -> physical
// (kq*4+quad)^(m&7): for fixed (mi,kq), 64 lanes spread 8 lanes/chunk
// uniformly over all 8 chunks = minimum bank cycles (enumerated).
// Staging (rule #21): gload_lds dest is the wave-uniform base
// &As[t*2048 + wave*512] (hardware deposits lane*16B linearly); the
// per-lane GLOBAL source is inverse-swizzled: lane's physical chunk
// p=lane&7 at row r=t*32+wave*8+(lane>>3) sources logical col-chunk
// p^(r&7). Accumulation k-order unchanged -> bit-identical output.
//
// QSCALE: cols<1024 (q part) scaled by log2(e)/8 after bias (exp2 trick).
// VT: blocks with col0>=2048 (V third of qkv) write their tile TRANSPOSED
//     to vt[b][h][d][t] via an LDS bounce and skip the qkvb store
//     (replaces the transpose_v kernel; proven in R4).
// ---------------------------------------------------------------------------
template <bool OUT_BF16, bool QSCALE, bool VT>
__global__ __launch_bounds__(256, 2)
void gemm_bt(const unsigned short* __restrict__ A, const unsigned short* __restrict__ Bw,
             const float* __restrict__ bias, void* __restrict__ Cout,
             unsigned short* __restrict__ vt, int N, int K) {
  __shared__ alignas(16) unsigned short As[128 * 64];
  __shared__ alignas(16) unsigned short Bs[128 * 64];
  const int tid = threadIdx.x;
  const int wave = tid >> 6, lane = tid & 63;
  const int l15 = lane & 15, quad = lane >> 4;
  const int wr = wave >> 1, wc = wave & 1;
  const int row0 = blockIdx.y * 128, col0 = blockIdx.x * 128;

  f32x4 acc[4][4];
#pragma unroll
  for (int i = 0; i < 4; ++i)
#pragma unroll
    for (int j = 0; j < 4; ++j) acc[i][j] = f32x4{0.f, 0.f, 0.f, 0.f};

  for (int k0 = 0; k0 < K; k0 += 64) {
#pragma unroll
    for (int t = 0; t < 4; ++t) {
      const int r = t * 32 + wave * 8 + (lane >> 3);   // row within tile
      const int l = (lane & 7) ^ (r & 7);              // logical col chunk
      gload_lds16(A  + (size_t)(row0 + r) * K + k0 + l * 8, &As[t * 2048 + wave * 512]);
      gload_lds16(Bw + (size_t)(col0 + r) * K + k0 + l * 8, &Bs[t * 2048 + wave * 512]);
    }
    __syncthreads();

#pragma unroll
    for (int kq = 0; kq < 2; ++kq) {
      bf16x8 af[4], bfr[4];
#pragma unroll
      for (int mi = 0; mi < 4; ++mi) {
        const int m = wr * 64 + mi * 16 + l15;
        af[mi] = *(const bf16x8*)&As[m * 64 + (((kq * 4 + quad) ^ (m & 7)) << 3)];
      }
#pragma unroll
      for (int ni = 0; ni < 4; ++ni) {
        const int n = wc * 64 + ni * 16 + l15;
        bfr[ni] = *(const bf16x8*)&Bs[n * 64 + (((kq * 4 + quad) ^ (n & 7)) << 3)];
      }
#pragma unroll
      for (int mi = 0; mi < 4; ++mi)
#pragma unroll
        for (int ni = 0; ni < 4; ++ni) acc[mi][ni] = mfma16(af[mi], bfr[ni], acc[mi][ni]);
    }
    __syncthreads();
  }

  if constexpr (VT) {
    if (col0 >= 2048) {
      // V-part: transposed store to vt[(b*16+h)*64 + d][t], two 64-col halves.
      __shared__ unsigned short Ct[64][136];
      const int b  = row0 >> 11;
      const int t0 = row0 & 2047;
#pragma unroll
      for (int hh = 0; hh < 2; ++hh) {
        __syncthreads();
        if (wc == hh) {
#pragma unroll
          for (int ni = 0; ni < 4; ++ni) {
            const int d = ni * 16 + l15;
            const float bv = bias[col0 + hh * 64 + d];
#pragma unroll
            for (int mi = 0; mi < 4; ++mi) {
              const int t = wr * 64 + mi * 16 + quad * 4;
              u16x4 wv;
#pragma unroll
              for (int r = 0; r < 4; ++r) wv[r] = f2bf(acc[mi][ni][r] + bv);
              *(u16x4*)&Ct[d][t] = wv;
            }
          }
        }
        __syncthreads();
        const int d = tid >> 2, tq = (tid & 3) * 32;
        const int bh = b * 16 + ((col0 - 2048) >> 6) + hh;
#pragma unroll
        for (int s = 0; s < 4; ++s)
          *(u16x8*)(vt + ((size_t)bh * 64 + d) * (size_t)Tt + t0 + tq + s * 8) =
              *(const u16x8*)&Ct[d][tq + s * 8];
      }
      return;
    }
  }

#pragma unroll
  for (int mi = 0; mi < 4; ++mi)
#pragma unroll
    for (int ni = 0; ni < 4; ++ni) {
      const int col = col0 + wc * 64 + ni * 16 + l15;
      const float bv = bias[col];
      const float scale = (QSCALE && col < 1024) ? 0.18033688f : 1.0f;  // log2(e)/8
#pragma unroll
      for (int r = 0; r < 4; ++r) {
        const int row = row0 + wr * 64 + mi * 16 + quad * 4 + r;
        float v = (acc[mi][ni][r] + bv) * scale;
        if (OUT_BF16)
          ((unsigned short*)Cout)[(size_t)row * N + col] = f2bf(v);
        else
          ((float*)Cout)[(size_t)row * N + col] = v;
      }
    }
}

// ---------------------------------------------------------------------------
// Fused attention, sub-tile software pipeline (proven 134 µs version).
// Wave = 64 q-rows x 2048 keys, barrier-free, per-wave-private LDS P slab
// (64x64 bf16, XOR-swizzled). 3 failed restructures (r1-r3) confirmed:
// deep prefetch + 4-chain ILP at 2 waves/SIMD beats any register-dieted
// higher-occupancy variant. Do not shrink per-wave state.
// ---------------------------------------------------------------------------
__global__ __launch_bounds__(256, 2)
void attn_mfma6(const unsigned short* __restrict__ qkv,
                const unsigned short* __restrict__ vt,
                unsigned short* __restrict__ ctx) {
  __shared__ alignas(16) unsigned short Ps[4 * 4096];  // per-wave 64x64 bf16
  const int tid = threadIdx.x;
  const int wave = tid >> 6, lane = tid & 63;
  const int l15 = lane & 15, quad = lane >> 4;
  const int bh = blockIdx.x, b = bh >> 4, h = bh & 15;
  const int q0 = blockIdx.y * 256 + wave * 64;
  unsigned short* const ps = &Ps[wave * 4096];
  const int swz = l15 & 14;

  bf16x8 qa[4][2];
#pragma unroll
  for (int qi = 0; qi < 4; ++qi)
#pragma unroll
    for (int kf = 0; kf < 2; ++kf)
      qa[qi][kf] = *(const bf16x8*)(qkv +
          (size_t)(b * Tt + q0 + qi * 16 + l15) * E3 + h * 64 + kf * 32 + quad * 8);

  f32x4 o[4][4], ol[4];
#pragma unroll
  for (int qi = 0; qi < 4; ++qi) {
    ol[qi] = f32x4{0.f, 0.f, 0.f, 0.f};
#pragma unroll
    for (int di = 0; di < 4; ++di) o[qi][di] = f32x4{0.f, 0.f, 0.f, 0.f};
  }
  bf16x8 ones;
#pragma unroll
  for (int i = 0; i < 8; ++i) ones[i] = (short)0x3F80;  // bf16 1.0

  const unsigned short* kp = qkv + (size_t)(b * Tt + l15) * E3 + Ee + h * 64 + quad * 8;
  const unsigned short* vp = vt + ((size_t)bh * 64 + l15) * Tt + quad * 8;

  bf16x8 kb[4][2], vb[4][2];
#pragma unroll
  for (int ki = 0; ki < 4; ++ki)
#pragma unroll
    for (int kf = 0; kf < 2; ++kf)
      kb[ki][kf] = *(const bf16x8*)(kp + (size_t)ki * 16 * E3 + kf * 32);
#pragma unroll
  for (int di = 0; di < 4; ++di)
#pragma unroll
    for (int kf = 0; kf < 2; ++kf)
      vb[di][kf] = *(const bf16x8*)(vp + di * 16 * Tt + kf * 32);
  kp += 64 * E3;   // -> tile 1 (reload source)
  vp += 64;        // -> tile 1 (next vb reload)

  f32x4 sp[4], sn[4];

  auto expwrite = [&](int slot) __attribute__((always_inline)) {
#pragma unroll
    for (int qi = 0; qi < 4; ++qi) {
      const float e0 = __builtin_amdgcn_exp2f(sp[qi][0]);
      const float e1 = __builtin_amdgcn_exp2f(sp[qi][1]);
      const float e2 = __builtin_amdgcn_exp2f(sp[qi][2]);
      const float e3 = __builtin_amdgcn_exp2f(sp[qi][3]);
      uint2 w;  // truncate-to-bf16 pairs (bias cancels: denom uses same P)
      w.x = __builtin_amdgcn_perm(__float_as_uint(e1), __float_as_uint(e0), 0x07060302u);
      w.y = __builtin_amdgcn_perm(__float_as_uint(e3), __float_as_uint(e2), 0x07060302u);
      *(uint2*)(ps + (qi * 16 + l15) * 64 + (((slot * 4 + quad) ^ swz) << 2)) = w;
    }
  };
  auto Sstep = [&](int ki) __attribute__((always_inline)) {
#pragma unroll
    for (int qi = 0; qi < 4; ++qi) {
      sn[qi] = mfma16(kb[ki][0], qa[qi][0], f32x4{0.f, 0.f, 0.f, 0.f});
      sn[qi] = mfma16(kb[ki][1], qa[qi][1], sn[qi]);
    }
  };
  auto copy_sp = [&]() __attribute__((always_inline)) {
#pragma unroll
    for (int qi = 0; qi < 4; ++qi) sp[qi] = sn[qi];
  };
  auto pvstep = [&](bool reload_vb) __attribute__((always_inline)) {
    __builtin_amdgcn_s_setprio(1);
#pragma unroll
    for (int qi = 0; qi < 4; ++qi) {
      bf16x8 pa0 = *(const bf16x8*)(ps + (qi * 16 + l15) * 64 + (((quad * 2) ^ swz) << 2));
      bf16x8 pa1 = *(const bf16x8*)(ps + (qi * 16 + l15) * 64 + (((8 + quad * 2) ^ swz) << 2));
      ol[qi] = mfma16(pa0, ones, ol[qi]);
      ol[qi] = mfma16(pa1, ones, ol[qi]);
#pragma unroll
      for (int di = 0; di < 4; ++di) {
        o[qi][di] = mfma16(pa0, vb[di][0], o[qi][di]);
        o[qi][di] = mfma16(pa1, vb[di][1], o[qi][di]);
      }
    }
    __builtin_amdgcn_s_setprio(0);
    if (reload_vb) {
#pragma unroll
      for (int di = 0; di < 4; ++di)
#pragma unroll
        for (int kf = 0; kf < 2; ++kf)
          vb[di][kf] = *(const bf16x8*)(vp + di * 16 * Tt + kf * 32);
      vp += 64;
    }
  };

  Sstep(0); copy_sp();
  kb[0][0] = *(const bf16x8*)(kp);
  kb[0][1] = *(const bf16x8*)(kp + 32);

  for (int j = 0; j < 31; ++j) {
    expwrite(0);
    Sstep(1);
    kb[1][0] = *(const bf16x8*)(kp + (size_t)16 * E3);
    kb[1][1] = *(const bf16x8*)(kp + (size_t)16 * E3 + 32);
    copy_sp();
    expwrite(1);
    Sstep(2);
    kb[2][0] = *(const bf16x8*)(kp + (size_t)32 * E3);
    kb[2][1] = *(const bf16x8*)(kp + (size_t)32 * E3 + 32);
    copy_sp();
    expwrite(2);
    Sstep(3);
    kb[3][0] = *(const bf16x8*)(kp + (size_t)48 * E3);
    kb[3][1] = *(const bf16x8*)(kp + (size_t)48 * E3 + 32);
    kp += 64 * E3;
    copy_sp();
    expwrite(3);
    Sstep(0);
    if (j < 30) {
      kb[0][0] = *(const bf16x8*)(kp);
      kb[0][1] = *(const bf16x8*)(kp + 32);
    }
    copy_sp();
    pvstep(true);
  }
  expwrite(0); Sstep(1); copy_sp();
  expwrite(1); Sstep(2); copy_sp();
  expwrite(2); Sstep(3); copy_sp();
  expwrite(3);
  pvstep(false);

#pragma unroll
  for (int qi = 0; qi < 4; ++qi) {
    f32x4 inv;
#pragma unroll
    for (int r = 0; r < 4; ++r) inv[r] = 1.0f / ol[qi][r];
#pragma unroll
    for (int di = 0; di < 4; ++di)
#pragma unroll
      for (int r = 0; r < 4; ++r)
        ctx[(size_t)(b * Tt + q0 + qi * 16 + quad * 4 + r) * Ee + h * 64 + di * 16 + l15] =
            f2bf(o[qi][di][r] * inv[r]);
  }
}

// ---------------------------------------------------------------------------
extern "C" void kernel_launch(void* const* d_in, const int* in_sizes, int n_in,
                              void* d_out, int out_size, void* d_ws, size_t ws_size,
                              hipStream_t stream) {
  const float* query = (const float*)d_in[0];
  const float* in_w  = (const float*)d_in[1];
  const float* in_b  = (const float*)d_in[2];
  const float* out_w = (const float*)d_in[3];
  const float* out_b = (const float*)d_in[4];
  float* out = (float*)d_out;

  char* w = (char*)d_ws;
  unsigned short* qkvb = (unsigned short*)(w);                 // 48 MiB
  unsigned short* ctxb = (unsigned short*)(w + 50331648);      // 16 MiB
  unsigned short* qb   = (unsigned short*)(w + 67108864);      // 16 MiB
  unsigned short* wib  = (unsigned short*)(w + 83886080);      // 6 MiB
  unsigned short* wob  = (unsigned short*)(w + 90177536);      // 2 MiB
  unsigned short* vtb  = (unsigned short*)(w + 92274688);      // 16 MiB

  // 0) all fp32->bf16 conversions in one launch
  cvt_all<<<6144, 256, 0, stream>>>(query, in_w, out_w, qb, wib, wob);
  // 1) qkv = query @ in_w^T + in_b (q part pre-scaled by log2e/8, bf16);
  //    BK=64; V third written TRANSPOSED to vtb in-epilogue
  gemm_bt<true, true, true><<<dim3(E3 / 128, Mm / 128), 256, 0, stream>>>(
      qb, wib, in_b, qkvb, vtb, E3, Ee);
  // 2) fused attention (64 q-rows/wave, proven pipeline) -> ctx
  attn_mfma6<<<dim3(Bb * Hh, Tt / 256), 256, 0, stream>>>(qkvb, vtb, ctxb);
  // 3) out = ctx @ out_w^T + out_b  (fp32 out, BK=64)
  gemm_bt<false, false, false><<<dim3(Ee / 128, Mm / 128), 256, 0, stream>>>(
      ctxb, wob, out_b, out, nullptr, Ee, Ee);
}

// Round 8
// 288.452 us; speedup vs baseline: 1.1147x; 1.0469x over previous
//
#include <hip/hip_runtime.h>
#include <math.h>

using bf16x8 = __attribute__((ext_vector_type(8))) short;
using f32x4  = __attribute__((ext_vector_type(4))) float;
using u16x8  = __attribute__((ext_vector_type(8))) unsigned short;
using u16x4  = __attribute__((ext_vector_type(4))) unsigned short;

constexpr int Bb = 4, Tt = 2048, Ee = 1024, Hh = 16;
constexpr int Mm = Bb * Tt;   // 8192
constexpr int E3 = 3 * Ee;    // 3072

__device__ __forceinline__ unsigned short f2bf(float f) {
  union { float f; unsigned int u; } c; c.f = f;
  unsigned int u = c.u;
  u += 0x7fffu + ((u >> 16) & 1u);   // RNE
  return (unsigned short)(u >> 16);
}

__device__ __forceinline__ f32x4 mfma16(bf16x8 a, bf16x8 b, f32x4 c) {
  return __builtin_amdgcn_mfma_f32_16x16x32_bf16(a, b, c, 0, 0, 0);
}

__device__ __forceinline__ void gload_lds16(const unsigned short* g, unsigned short* l) {
  __builtin_amdgcn_global_load_lds(
      (const __attribute__((address_space(1))) unsigned int*)g,
      (__attribute__((address_space(3))) unsigned int*)l, 16, 0, 0);
}

// ---------------------------------------------------------------------------
// fused fp32 -> bf16 conversion for all three inputs (one launch)
// ---------------------------------------------------------------------------
__global__ void cvt_all(const float* __restrict__ q, const float* __restrict__ iw,
                        const float* __restrict__ ow, unsigned short* __restrict__ qb,
                        unsigned short* __restrict__ wib, unsigned short* __restrict__ wob) {
  constexpr int nQ = Mm * Ee / 8, nI = E3 * Ee / 8, nO = Ee * Ee / 8;
  int i = blockIdx.x * 256 + threadIdx.x;
  const float* in; unsigned short* out;
  if (i < nQ) { in = q; out = qb; }
  else if (i < nQ + nI) { in = iw; out = wib; i -= nQ; }
  else if (i < nQ + nI + nO) { in = ow; out = wob; i -= nQ + nI; }
  else return;
  const float4* p = (const float4*)in + (size_t)i * 2;
  const float4 a = p[0], b = p[1];
  u16x8 r = { f2bf(a.x), f2bf(a.y), f2bf(a.z), f2bf(a.w),
              f2bf(b.x), f2bf(b.y), f2bf(b.z), f2bf(b.w) };
  *(u16x8*)(out + (size_t)i * 8) = r;
}

// ---------------------------------------------------------------------------
// C[M,N] = A[M,K] * Bw[N,K]^T + bias  (bf16 MFMA, m97-style, BK=64).
//
// R7: BK=64 (confirmed +7 us). R8: L2-aware XCD super-tiling -- gemm1's B
// panel (6 MB bf16) EXCEEDS one XCD's 4 MB L2; default x-fastest dispatch
// makes every XCD touch all of B -> L2 thrash, staging from L3.
// Fix (indexing only): 1-D grid, bid&7 = XCD (round-robin HW assignment)
// owns row-super rs (8 row tiles, A slice 2 MB, L2-resident across all
// phases); within an XCD, 64-block groups sweep col-supers of 8 col tiles
// (B slice 2 MB). Resident set/XCD = 4 MB = exactly L2. All 8 XCDs read
// the same B col-super in lock-phase (L3 broadcast). Bijective for
// rowtiles == 64 and cols % 8 == 0 (gemm1: 24 cols, gemm2: 8 cols).
//
// LDS layout at BK=64: [128 rows][64 ushort], physical 16B chunk p of row r
// holds logical chunk p ^ (r&7); read at logical (kq*4+quad) -> physical
// ^(m&7) = uniform 8 lanes/chunk (conflict-free). Staging dest is the
// wave-uniform linear base (rule #21); per-lane GLOBAL source is
// inverse-swizzled. Accumulation k-order unchanged -> bit-identical output.
//
// QSCALE: cols<1024 (q part) scaled by log2(e)/8 after bias (exp2 trick).
// VT: blocks with col0>=2048 (V third of qkv) write their tile TRANSPOSED
//     to vt[b][h][d][t] via an LDS bounce and skip the qkvb store.
// ---------------------------------------------------------------------------
template <bool OUT_BF16, bool QSCALE, bool VT>
__global__ __launch_bounds__(256, 2)
void gemm_bt(const unsigned short* __restrict__ A, const unsigned short* __restrict__ Bw,
             const float* __restrict__ bias, void* __restrict__ Cout,
             unsigned short* __restrict__ vt, int N, int K) {
  __shared__ alignas(16) unsigned short As[128 * 64];
  __shared__ alignas(16) unsigned short Bs[128 * 64];
  const int tid = threadIdx.x;
  const int wave = tid >> 6, lane = tid & 63;
  const int l15 = lane & 15, quad = lane >> 4;
  const int wr = wave >> 1, wc = wave & 1;

  // L2-aware XCD super-tile mapping (M/128 == 64 row tiles assumed).
  const int bid = blockIdx.x;
  const int rs = bid & 7;            // row-super == XCD (round-robin)
  const int s  = bid >> 3;
  const int cs = s >> 6;             // col-super (64 blocks each)
  const int w  = s & 63;
  const int row0 = (rs * 8 + (w & 7)) * 128;
  const int col0 = (cs * 8 + (w >> 3)) * 128;

  f32x4 acc[4][4];
#pragma unroll
  for (int i = 0; i < 4; ++i)
#pragma unroll
    for (int j = 0; j < 4; ++j) acc[i][j] = f32x4{0.f, 0.f, 0.f, 0.f};

  for (int k0 = 0; k0 < K; k0 += 64) {
#pragma unroll
    for (int t = 0; t < 4; ++t) {
      const int r = t * 32 + wave * 8 + (lane >> 3);   // row within tile
      const int l = (lane & 7) ^ (r & 7);              // logical col chunk
      gload_lds16(A  + (size_t)(row0 + r) * K + k0 + l * 8, &As[t * 2048 + wave * 512]);
      gload_lds16(Bw + (size_t)(col0 + r) * K + k0 + l * 8, &Bs[t * 2048 + wave * 512]);
    }
    __syncthreads();

#pragma unroll
    for (int kq = 0; kq < 2; ++kq) {
      bf16x8 af[4], bfr[4];
#pragma unroll
      for (int mi = 0; mi < 4; ++mi) {
        const int m = wr * 64 + mi * 16 + l15;
        af[mi] = *(const bf16x8*)&As[m * 64 + (((kq * 4 + quad) ^ (m & 7)) << 3)];
      }
#pragma unroll
      for (int ni = 0; ni < 4; ++ni) {
        const int n = wc * 64 + ni * 16 + l15;
        bfr[ni] = *(const bf16x8*)&Bs[n * 64 + (((kq * 4 + quad) ^ (n & 7)) << 3)];
      }
#pragma unroll
      for (int mi = 0; mi < 4; ++mi)
#pragma unroll
        for (int ni = 0; ni < 4; ++ni) acc[mi][ni] = mfma16(af[mi], bfr[ni], acc[mi][ni]);
    }
    __syncthreads();
  }

  if constexpr (VT) {
    if (col0 >= 2048) {
      // V-part: transposed store to vt[(b*16+h)*64 + d][t], two 64-col halves.
      __shared__ unsigned short Ct[64][136];
      const int b  = row0 >> 11;
      const int t0 = row0 & 2047;
#pragma unroll
      for (int hh = 0; hh < 2; ++hh) {
        __syncthreads();
        if (wc == hh) {
#pragma unroll
          for (int ni = 0; ni < 4; ++ni) {
            const int d = ni * 16 + l15;
            const float bv = bias[col0 + hh * 64 + d];
#pragma unroll
            for (int mi = 0; mi < 4; ++mi) {
              const int t = wr * 64 + mi * 16 + quad * 4;
              u16x4 wv;
#pragma unroll
              for (int r = 0; r < 4; ++r) wv[r] = f2bf(acc[mi][ni][r] + bv);
              *(u16x4*)&Ct[d][t] = wv;
            }
          }
        }
        __syncthreads();
        const int d = tid >> 2, tq = (tid & 3) * 32;
        const int bh = b * 16 + ((col0 - 2048) >> 6) + hh;
#pragma unroll
        for (int sid = 0; sid < 4; ++sid)
          *(u16x8*)(vt + ((size_t)bh * 64 + d) * (size_t)Tt + t0 + tq + sid * 8) =
              *(const u16x8*)&Ct[d][tq + sid * 8];
      }
      return;
    }
  }

#pragma unroll
  for (int mi = 0; mi < 4; ++mi)
#pragma unroll
    for (int ni = 0; ni < 4; ++ni) {
      const int col = col0 + wc * 64 + ni * 16 + l15;
      const float bv = bias[col];
      const float scale = (QSCALE && col < 1024) ? 0.18033688f : 1.0f;  // log2(e)/8
#pragma unroll
      for (int r = 0; r < 4; ++r) {
        const int row = row0 + wr * 64 + mi * 16 + quad * 4 + r;
        float v = (acc[mi][ni][r] + bv) * scale;
        if (OUT_BF16)
          ((unsigned short*)Cout)[(size_t)row * N + col] = f2bf(v);
        else
          ((float*)Cout)[(size_t)row * N + col] = v;
      }
    }
}

// ---------------------------------------------------------------------------
// Fused attention, sub-tile software pipeline (proven 134 µs version).
// Wave = 64 q-rows x 2048 keys, barrier-free, per-wave-private LDS P slab
// (64x64 bf16, XOR-swizzled). 3 failed restructures (r1-r3) confirmed:
// deep prefetch + 4-chain ILP at 2 waves/SIMD beats any register-dieted
// higher-occupancy variant. Do not shrink per-wave state.
// ---------------------------------------------------------------------------
__global__ __launch_bounds__(256, 2)
void attn_mfma6(const unsigned short* __restrict__ qkv,
                const unsigned short* __restrict__ vt,
                unsigned short* __restrict__ ctx) {
  __shared__ alignas(16) unsigned short Ps[4 * 4096];  // per-wave 64x64 bf16
  const int tid = threadIdx.x;
  const int wave = tid >> 6, lane = tid & 63;
  const int l15 = lane & 15, quad = lane >> 4;
  const int bh = blockIdx.x, b = bh >> 4, h = bh & 15;
  const int q0 = blockIdx.y * 256 + wave * 64;
  unsigned short* const ps = &Ps[wave * 4096];
  const int swz = l15 & 14;

  bf16x8 qa[4][2];
#pragma unroll
  for (int qi = 0; qi < 4; ++qi)
#pragma unroll
    for (int kf = 0; kf < 2; ++kf)
      qa[qi][kf] = *(const bf16x8*)(qkv +
          (size_t)(b * Tt + q0 + qi * 16 + l15) * E3 + h * 64 + kf * 32 + quad * 8);

  f32x4 o[4][4], ol[4];
#pragma unroll
  for (int qi = 0; qi < 4; ++qi) {
    ol[qi] = f32x4{0.f, 0.f, 0.f, 0.f};
#pragma unroll
    for (int di = 0; di < 4; ++di) o[qi][di] = f32x4{0.f, 0.f, 0.f, 0.f};
  }
  bf16x8 ones;
#pragma unroll
  for (int i = 0; i < 8; ++i) ones[i] = (short)0x3F80;  // bf16 1.0

  const unsigned short* kp = qkv + (size_t)(b * Tt + l15) * E3 + Ee + h * 64 + quad * 8;
  const unsigned short* vp = vt + ((size_t)bh * 64 + l15) * Tt + quad * 8;

  bf16x8 kb[4][2], vb[4][2];
#pragma unroll
  for (int ki = 0; ki < 4; ++ki)
#pragma unroll
    for (int kf = 0; kf < 2; ++kf)
      kb[ki][kf] = *(const bf16x8*)(kp + (size_t)ki * 16 * E3 + kf * 32);
#pragma unroll
  for (int di = 0; di < 4; ++di)
#pragma unroll
    for (int kf = 0; kf < 2; ++kf)
      vb[di][kf] = *(const bf16x8*)(vp + di * 16 * Tt + kf * 32);
  kp += 64 * E3;   // -> tile 1 (reload source)
  vp += 64;        // -> tile 1 (next vb reload)

  f32x4 sp[4], sn[4];

  auto expwrite = [&](int slot) __attribute__((always_inline)) {
#pragma unroll
    for (int qi = 0; qi < 4; ++qi) {
      const float e0 = __builtin_amdgcn_exp2f(sp[qi][0]);
      const float e1 = __builtin_amdgcn_exp2f(sp[qi][1]);
      const float e2 = __builtin_amdgcn_exp2f(sp[qi][2]);
      const float e3 = __builtin_amdgcn_exp2f(sp[qi][3]);
      uint2 w;  // truncate-to-bf16 pairs (bias cancels: denom uses same P)
      w.x = __builtin_amdgcn_perm(__float_as_uint(e1), __float_as_uint(e0), 0x07060302u);
      w.y = __builtin_amdgcn_perm(__float_as_uint(e3), __float_as_uint(e2), 0x07060302u);
      *(uint2*)(ps + (qi * 16 + l15) * 64 + (((slot * 4 + quad) ^ swz) << 2)) = w;
    }
  };
  auto Sstep = [&](int ki) __attribute__((always_inline)) {
#pragma unroll
    for (int qi = 0; qi < 4; ++qi) {
      sn[qi] = mfma16(kb[ki][0], qa[qi][0], f32x4{0.f, 0.f, 0.f, 0.f});
      sn[qi] = mfma16(kb[ki][1], qa[qi][1], sn[qi]);
    }
  };
  auto copy_sp = [&]() __attribute__((always_inline)) {
#pragma unroll
    for (int qi = 0; qi < 4; ++qi) sp[qi] = sn[qi];
  };
  auto pvstep = [&](bool reload_vb) __attribute__((always_inline)) {
    __builtin_amdgcn_s_setprio(1);
#pragma unroll
    for (int qi = 0; qi < 4; ++qi) {
      bf16x8 pa0 = *(const bf16x8*)(ps + (qi * 16 + l15) * 64 + (((quad * 2) ^ swz) << 2));
      bf16x8 pa1 = *(const bf16x8*)(ps + (qi * 16 + l15) * 64 + (((8 + quad * 2) ^ swz) << 2));
      ol[qi] = mfma16(pa0, ones, ol[qi]);
      ol[qi] = mfma16(pa1, ones, ol[qi]);
#pragma unroll
      for (int di = 0; di < 4; ++di) {
        o[qi][di] = mfma16(pa0, vb[di][0], o[qi][di]);
        o[qi][di] = mfma16(pa1, vb[di][1], o[qi][di]);
      }
    }
    __builtin_amdgcn_s_setprio(0);
    if (reload_vb) {
#pragma unroll
      for (int di = 0; di < 4; ++di)
#pragma unroll
        for (int kf = 0; kf < 2; ++kf)
          vb[di][kf] = *(const bf16x8*)(vp + di * 16 * Tt + kf * 32);
      vp += 64;
    }
  };

  Sstep(0); copy_sp();
  kb[0][0] = *(const bf16x8*)(kp);
  kb[0][1] = *(const bf16x8*)(kp + 32);

  for (int j = 0; j < 31; ++j) {
    expwrite(0);
    Sstep(1);
    kb[1][0] = *(const bf16x8*)(kp + (size_t)16 * E3);
    kb[1][1] = *(const bf16x8*)(kp + (size_t)16 * E3 + 32);
    copy_sp();
    expwrite(1);
    Sstep(2);
    kb[2][0] = *(const bf16x8*)(kp + (size_t)32 * E3);
    kb[2][1] = *(const bf16x8*)(kp + (size_t)32 * E3 + 32);
    copy_sp();
    expwrite(2);
    Sstep(3);
    kb[3][0] = *(const bf16x8*)(kp + (size_t)48 * E3);
    kb[3][1] = *(const bf16x8*)(kp + (size_t)48 * E3 + 32);
    kp += 64 * E3;
    copy_sp();
    expwrite(3);
    Sstep(0);
    if (j < 30) {
      kb[0][0] = *(const bf16x8*)(kp);
      kb[0][1] = *(const bf16x8*)(kp + 32);
    }
    copy_sp();
    pvstep(true);
  }
  expwrite(0); Sstep(1); copy_sp();
  expwrite(1); Sstep(2); copy_sp();
  expwrite(2); Sstep(3); copy_sp();
  expwrite(3);
  pvstep(false);

#pragma unroll
  for (int qi = 0; qi < 4; ++qi) {
    f32x4 inv;
#pragma unroll
    for (int r = 0; r < 4; ++r) inv[r] = 1.0f / ol[qi][r];
#pragma unroll
    for (int di = 0; di < 4; ++di)
#pragma unroll
      for (int r = 0; r < 4; ++r)
        ctx[(size_t)(b * Tt + q0 + qi * 16 + quad * 4 + r) * Ee + h * 64 + di * 16 + l15] =
            f2bf(o[qi][di][r] * inv[r]);
  }
}

// ---------------------------------------------------------------------------
extern "C" void kernel_launch(void* const* d_in, const int* in_sizes, int n_in,
                              void* d_out, int out_size, void* d_ws, size_t ws_size,
                              hipStream_t stream) {
  const float* query = (const float*)d_in[0];
  const float* in_w  = (const float*)d_in[1];
  const float* in_b  = (const float*)d_in[2];
  const float* out_w = (const float*)d_in[3];
  const float* out_b = (const float*)d_in[4];
  float* out = (float*)d_out;

  char* w = (char*)d_ws;
  unsigned short* qkvb = (unsigned short*)(w);                 // 48 MiB
  unsigned short* ctxb = (unsigned short*)(w + 50331648);      // 16 MiB
  unsigned short* qb   = (unsigned short*)(w + 67108864);      // 16 MiB
  unsigned short* wib  = (unsigned short*)(w + 83886080);      // 6 MiB
  unsigned short* wob  = (unsigned short*)(w + 90177536);      // 2 MiB
  unsigned short* vtb  = (unsigned short*)(w + 92274688);      // 16 MiB

  // 0) all fp32->bf16 conversions in one launch
  cvt_all<<<6144, 256, 0, stream>>>(query, in_w, out_w, qb, wib, wob);
  // 1) qkv = query @ in_w^T + in_b (q part pre-scaled by log2e/8, bf16);
  //    BK=64, L2-aware XCD super-tiling; V third TRANSPOSED to vtb in-epilogue
  gemm_bt<true, true, true><<<dim3((E3 / 128) * (Mm / 128)), 256, 0, stream>>>(
      qb, wib, in_b, qkvb, vtb, E3, Ee);
  // 2) fused attention (64 q-rows/wave, proven pipeline) -> ctx
  attn_mfma6<<<dim3(Bb * Hh, Tt / 256), 256, 0, stream>>>(qkvb, vtb, ctxb);
  // 3) out = ctx @ out_w^T + out_b  (fp32 out, BK=64, same super-tiling)
  gemm_bt<false, false, false><<<dim3((Ee / 128) * (Mm / 128)), 256, 0, stream>>>(
      ctxb, wob, out_b, out, nullptr, Ee, Ee);
}